// Round 11
// baseline (40.856 us; speedup 1.0000x reference)
//
#include <hip/hip_runtime.h>

#define W 512
#define NPIX 4194304              // 16 images * 512*512, per input

union Bytes { uint4 v; unsigned char b[16]; };

__device__ __forceinline__ unsigned char gray1(float a, float b, float c) {
    // JAX f32 op order: ((c0+c1+c2)/3)*255, round-nearest-even
    return (unsigned char)__float2int_rn(((a + b + c) / 3.0f) * 255.0f);
}

// ---------------------------------------------------------------------------
// K1: per block = one 16-row tile of one image of one input (grid 512 x 2).
// launch_bounds(256,4) -> VGPR cap 128; staging software-pipelined depth 1.
//   - gray rows r0-1..r0+16 (18 rows incl. recomputed halo) -> LDS
//   - store main 16 rows to global gray buffer
//   - per-block min/max of joint = center*256 + shifted, 4 shifts
//     SHIFTS=(1,0),(1,1),(0,1),(-1,1); shifted[r,c]=g[(r-dx)&511,(c-dy)&511]
//   - 8 u32 per block to distinct global slots (no atomics)
// (R10-proven; k1 sits at its memory floor.)
// ---------------------------------------------------------------------------
__global__ __launch_bounds__(256, 4) void k1_gray_minmax(
    const float4* __restrict__ og, const float4* __restrict__ gg,
    uchar4* __restrict__ gray, unsigned int* __restrict__ blockmm) {
    int inp = blockIdx.y;
    int img = blockIdx.x >> 5;
    int r0 = (blockIdx.x & 31) << 4;
    const float4* src = (inp ? gg : og) + (size_t)img * 3 * 65536;
    uchar4* gout = gray + (size_t)inp * (NPIX / 4) + img * 65536;
    const float4* s0 = src;
    const float4* s1 = src + 65536;
    const float4* s2 = src + 131072;

    __shared__ unsigned char lds[18 * W];
    uchar4* lds4 = (uchar4*)lds;

    int off[9];
#pragma unroll
    for (int j = 0; j < 9; ++j) {
        int q = threadIdx.x + j * 256;
        int i = q >> 7, quad = q & 127;
        int ir = (r0 - 1 + i) & 511;
        off[j] = ir * 128 + quad;
    }
    float4 a = s0[off[0]], b = s1[off[0]], c = s2[off[0]];
#pragma unroll
    for (int j = 0; j < 9; ++j) {
        float4 an, bn, cn;
        if (j < 8) { an = s0[off[j + 1]]; bn = s1[off[j + 1]]; cn = s2[off[j + 1]]; }
        uchar4 r;
        r.x = gray1(a.x, b.x, c.x);
        r.y = gray1(a.y, b.y, c.y);
        r.z = gray1(a.z, b.z, c.z);
        r.w = gray1(a.w, b.w, c.w);
        lds4[threadIdx.x + j * 256] = r;
        int i = (threadIdx.x + j * 256) >> 7;
        if (i >= 1 && i <= 16) gout[off[j]] = r;   // main rows only
        a = an; b = bn; c = cn;
    }
    __syncthreads();

    int lr = 1 + (threadIdx.x >> 4);
    int c0 = (threadIdx.x & 15) << 5;
    const unsigned char* Lm = lds + (lr - 1) * W;
    const unsigned char* Lc = lds + lr * W;
    const unsigned char* Lp = lds + (lr + 1) * W;
    Bytes rm[2], rc[2], rp[2];
    rm[0].v = *(const uint4*)(Lm + c0); rm[1].v = *(const uint4*)(Lm + c0 + 16);
    rc[0].v = *(const uint4*)(Lc + c0); rc[1].v = *(const uint4*)(Lc + c0 + 16);
    rp[0].v = *(const uint4*)(Lp + c0); rp[1].v = *(const uint4*)(Lp + c0 + 16);
    int cp = (c0 - 1) & 511;
    unsigned char pm = Lm[cp], pc = Lc[cp], pp = Lp[cp];

    unsigned int lmin[4] = {~0u, ~0u, ~0u, ~0u};
    unsigned int lmax[4] = {0u, 0u, 0u, 0u};
#pragma unroll
    for (int h = 0; h < 2; ++h) {
#pragma unroll
        for (int j = 0; j < 16; ++j) {
            unsigned int base = ((unsigned int)rc[h].b[j]) << 8;
            unsigned int v0 = base + rm[h].b[j];
            unsigned int v1 = base + (j ? rm[h].b[j - 1] : (h ? rm[0].b[15] : pm));
            unsigned int v2 = base + (j ? rc[h].b[j - 1] : (h ? rc[0].b[15] : pc));
            unsigned int v3 = base + (j ? rp[h].b[j - 1] : (h ? rp[0].b[15] : pp));
            lmin[0] = min(lmin[0], v0); lmax[0] = max(lmax[0], v0);
            lmin[1] = min(lmin[1], v1); lmax[1] = max(lmax[1], v1);
            lmin[2] = min(lmin[2], v2); lmax[2] = max(lmax[2], v2);
            lmin[3] = min(lmin[3], v3); lmax[3] = max(lmax[3], v3);
        }
    }
#pragma unroll
    for (int off2 = 32; off2 > 0; off2 >>= 1) {
#pragma unroll
        for (int s = 0; s < 4; ++s) {
            lmin[s] = min(lmin[s], (unsigned int)__shfl_down((int)lmin[s], off2));
            lmax[s] = max(lmax[s], (unsigned int)__shfl_down((int)lmax[s], off2));
        }
    }
    __shared__ unsigned int wmin[4][4], wmax[4][4];
    int wave = threadIdx.x >> 6;
    if ((threadIdx.x & 63) == 0) {
#pragma unroll
        for (int s = 0; s < 4; ++s) { wmin[wave][s] = lmin[s]; wmax[wave][s] = lmax[s]; }
    }
    __syncthreads();
    if (threadIdx.x < 4) {
        int s = threadIdx.x;
        unsigned int mn = min(min(wmin[0][s], wmin[1][s]), min(wmin[2][s], wmin[3][s]));
        unsigned int mx = max(max(wmax[0][s], wmax[1][s]), max(wmax[2][s], wmax[3][s]));
        blockmm[inp * 4096 + s * 512 + blockIdx.x] = mn;
        blockmm[inp * 4096 + (4 + s) * 512 + blockIdx.x] = mx;
    }
}

// ---------------------------------------------------------------------------
// K2: DIRECT-LOAD contrast (no LDS tile, no staging sync).
// grid (1024, 2) = 2048 blocks = 8 blocks/CU -> 32 waves/CU (2x R10).
// Each thread owns one 16-px row segment: loads rows r-1, r, r+1 as uint4
// (+3 boundary bytes) straight from L2/L3-resident gray; loads are issued
// before the minmax-table reduce so they overlap it.
//   per-pixel: t = (float)(v - vmin); b = min((int)(t*scale), 65535)
//   [t>=0 so trunc==floor, no lower clamp]; d=(b>>8)-(b&255); sum d^2 in u32.
//   4 per-block partial sums to distinct slots (no atomics).
// ---------------------------------------------------------------------------
__global__ __launch_bounds__(256, 8) void k2_contrast(
    const unsigned char* __restrict__ gray,
    const unsigned int* __restrict__ blockmm,
    unsigned int* __restrict__ partial) {
    int inp = blockIdx.y;
    const unsigned char* g = gray + (size_t)inp * NPIX;
    int t = blockIdx.x * 256 + threadIdx.x;   // segment id, 262144 per input
    int img = t >> 14;                        // 16384 segments per image
    int p = t & 16383;
    int r = p >> 5;                           // 32 segments per row
    int c0 = (p & 31) << 4;
    const unsigned char* gn = g + (img << 18);
    int rm1 = (r - 1) & 511, rp1 = (r + 1) & 511, cp = (c0 - 1) & 511;

    // issue all 6 independent loads first (overlap the table reduce below)
    Bytes rm, rc, rp;
    rm.v = *(const uint4*)(gn + (rm1 << 9) + c0);
    rc.v = *(const uint4*)(gn + (r   << 9) + c0);
    rp.v = *(const uint4*)(gn + (rp1 << 9) + c0);
    unsigned char pm = gn[(rm1 << 9) | cp];
    unsigned char pc = gn[(r   << 9) | cp];
    unsigned char pp = gn[(rp1 << 9) | cp];

    // redundant reduce of this input's 512x8 minmax table (L2-resident)
    __shared__ unsigned int mmfin[8];
    {
        int s8 = threadIdx.x >> 5, lane = threadIdx.x & 31;
        const unsigned int* mb = blockmm + inp * 4096 + s8 * 512;
        unsigned int v = mb[lane];
#pragma unroll
        for (int k = 1; k < 16; ++k) {
            unsigned int u = mb[lane + k * 32];
            v = (s8 < 4) ? min(v, u) : max(v, u);
        }
#pragma unroll
        for (int off = 16; off > 0; off >>= 1) {
            unsigned int u = (unsigned int)__shfl_down((int)v, off, 32);
            v = (s8 < 4) ? min(v, u) : max(v, u);
        }
        if (lane == 0) mmfin[s8] = v;
    }
    __syncthreads();

    unsigned int vm[4]; float scale[4];
#pragma unroll
    for (int s = 0; s < 4; ++s) {
        vm[s] = mmfin[s];
        scale[s] = 65536.0f / fmaxf((float)(mmfin[4 + s] - vm[s]), 1.0f);
    }

    unsigned int acc[4] = {0u, 0u, 0u, 0u};
#pragma unroll
    for (int j = 0; j < 16; ++j) {
        unsigned int base = ((unsigned int)rc.b[j]) << 8;
        unsigned int v[4];
        v[0] = base + rm.b[j];
        v[1] = base + (j ? rm.b[j - 1] : pm);
        v[2] = base + (j ? rc.b[j - 1] : pc);
        v[3] = base + (j ? rp.b[j - 1] : pp);
#pragma unroll
        for (int s = 0; s < 4; ++s) {
            int b = (int)((float)(v[s] - vm[s]) * scale[s]);  // t>=0: trunc==floor
            b = b > 65535 ? 65535 : b;
            int d = (b >> 8) - (b & 255);
            acc[s] += (unsigned int)(d * d);
        }
    }
#pragma unroll
    for (int off = 32; off > 0; off >>= 1)
#pragma unroll
        for (int s = 0; s < 4; ++s)
            acc[s] += (unsigned int)__shfl_down((int)acc[s], off);

    __shared__ unsigned int wsum[4][4];
    int wave = threadIdx.x >> 6;
    if ((threadIdx.x & 63) == 0) {
#pragma unroll
        for (int s = 0; s < 4; ++s) wsum[wave][s] = acc[s];
    }
    __syncthreads();
    if (threadIdx.x < 4) {
        int s = threadIdx.x;
        unsigned int tot = wsum[0][s] + wsum[1][s] + wsum[2][s] + wsum[3][s];
        partial[(inp * 4 + s) * 1024 + blockIdx.x] = tot;
    }
}

// ---------------------------------------------------------------------------
// K3: one block. Reduce 8 combos x 1024 partials (double, exact < 2^53),
// loss = mean_a |2*S_og/2^25 - 2*S_gg/2^25|
// ---------------------------------------------------------------------------
__global__ __launch_bounds__(256) void k3_loss(
    const unsigned int* __restrict__ partial, float* __restrict__ out) {
    int c = threadIdx.x >> 5;       // combo = inp*4 + s
    int lane = threadIdx.x & 31;
    const unsigned int* p = partial + c * 1024;
    double acc = 0.0;
#pragma unroll
    for (int k = 0; k < 32; ++k) acc += (double)p[lane + k * 32];
#pragma unroll
    for (int off = 16; off > 0; off >>= 1) acc += __shfl_down(acc, off, 32);
    __shared__ double cs[8];
    if (lane == 0) cs[c] = acc;
    __syncthreads();
    if (threadIdx.x == 0) {
        double r = 0.0;
        for (int a = 0; a < 4; ++a) {
            double co = 2.0 * cs[a]     / 33554432.0;
            double cg = 2.0 * cs[4 + a] / 33554432.0;
            r += fabs(co - cg);
        }
        out[0] = (float)(r * 0.25);
    }
}

extern "C" void kernel_launch(void* const* d_in, const int* in_sizes, int n_in,
                              void* d_out, int out_size, void* d_ws, size_t ws_size,
                              hipStream_t stream) {
    const float4* og = (const float4*)d_in[0];
    const float4* gg = (const float4*)d_in[1];
    float* out = (float*)d_out;

    // ws: blockmm u32[8192] @0 (32KB) | partial u32[8192] @32KB (32KB)
    //     | gray @64KB (8MB)
    unsigned int* blockmm = (unsigned int*)d_ws;
    unsigned int* partial = blockmm + 8192;
    unsigned char* gray = (unsigned char*)d_ws + 65536;

    dim3 g1(512, 2);
    k1_gray_minmax<<<g1, 256, 0, stream>>>(og, gg, (uchar4*)gray, blockmm);
    dim3 g2(1024, 2);
    k2_contrast<<<g2, 256, 0, stream>>>(gray, blockmm, partial);
    k3_loss<<<1, 256, 0, stream>>>(partial, out);
}